// Round 13
// baseline (476.069 us; speedup 1.0000x reference)
//
#include <hip/hip_runtime.h>
#include <cstdint>

// Problem constants (match reference)
#define Bn 8
#define Ln 4096
#define Dn 2048
#define Gn 32
#define GSn 64
#define Rn 8                     // rows (timesteps) per chunk; 512 threads x f4 = 1 row
#define CPB (Ln / Rn)            // 512 chunks per batch
#define NCHUNK (Bn * CPB)        // 4096 chunks total
static constexpr float EPS = 1e-5f;

// Native vector type for nontemporal builtins (HIP float4 is rejected).
typedef float f4 __attribute__((ext_vector_type(4)));

// ---------------------------------------------------------------------------
// init: zero lookback flags + ticket counter (ws is poisoned 0xAA; graph
// replays reuse it, so state must be re-zeroed every call).
// ---------------------------------------------------------------------------
__global__ __launch_bounds__(512) void k_init(unsigned* __restrict__ flags,
                                              unsigned* __restrict__ ticket) {
    const int i = blockIdx.x * 512 + threadIdx.x;
    if (i < NCHUNK) flags[i] = 0u;
    if (i == 0) *ticket = 0u;
}

// ---------------------------------------------------------------------------
// Contiguous-stream scan+normalize with decoupled lookback.
// Block -> ticket -> chunk T; b = T/CPB, c = T%CPB; rows [c*8, c*8+8) of b.
// 1) nt-load 8 contiguous rows (64KB) into registers (f4/thread/row).
// 2) per-row group means via 16-lane shfl_xor -> LDS.
// 3) threads 0..255 (g,r): masked (S,Q,P), width-8 segmented scan over rows;
//    row-7 lanes hold the chunk aggregate -> publish (relaxed agent atomics).
// 4) barrier (drains vmcnt -> aggs at coherence point); flag=AGGREGATE
//    (release); wave0 lanes g: lookback over predecessors (relaxed polls,
//    s_sleep; INCLUSIVE short-circuit); publish inclusive; flag=INCLUSIVE.
//    Ticket order == start order => predecessors have started => no deadlock.
// 5) per-(row,g) closed-form Welford -> mean/rstd in LDS.
// 6) normalize payload from registers, nt-store 8 contiguous rows.
// x read once, y written once, both fully contiguous per block.
// mask (bool) and prev_count (int64) are pushed by the harness as int32.
// ---------------------------------------------------------------------------
__global__ __launch_bounds__(512, 4) void scan_norm(
    const float* __restrict__ x,
    const int* __restrict__ mask,
    const int* __restrict__ prev_count,
    const float* __restrict__ prev_mean,
    const float* __restrict__ prev_var,
    const float* __restrict__ weight,
    const float* __restrict__ bias,
    float* __restrict__ y,
    float* __restrict__ out_count,
    float* __restrict__ out_mean,
    float* __restrict__ out_var,
    unsigned* __restrict__ ticket,
    unsigned* __restrict__ flags,
    float* __restrict__ aggS, float* __restrict__ aggQ, float* __restrict__ aggP,
    float* __restrict__ incS, float* __restrict__ incQ, float* __restrict__ incP)
{
    const int tid = threadIdx.x;
    __shared__ unsigned sT;
    if (tid == 0)
        sT = __hip_atomic_fetch_add(ticket, 1u, __ATOMIC_RELAXED, __HIP_MEMORY_SCOPE_AGENT);
    __syncthreads();
    const int T = (int)sT;
    const int b = T >> 9;                 // T / CPB (CPB = 512)
    const int c = T & (CPB - 1);
    const int row0 = b * Ln + c * Rn;     // global row index of chunk start

    // ---- payload: 8 contiguous rows, this thread's 16-B column
    f4 xv[Rn];
    {
        const float* xp = x + (size_t)row0 * Dn + tid * 4;
#pragma unroll
        for (int i = 0; i < Rn; ++i)
            xv[i] = __builtin_nontemporal_load(reinterpret_cast<const f4*>(xp + (size_t)i * Dn));
    }
    const f4 w4 = *reinterpret_cast<const f4*>(weight + tid * 4);
    const f4 b4 = *reinterpret_cast<const f4*>(bias + tid * 4);

    __shared__ float m_l[Rn][Gn];
    __shared__ float iS_l[Rn][Gn], iQ_l[Rn][Gn], iP_l[Rn][Gn];
    __shared__ float aS_l[Gn], aQ_l[Gn], aP_l[Gn];
    __shared__ float eS_l[Gn], eQ_l[Gn], eP_l[Gn];
    __shared__ float me_l[Rn][Gn], rs_l[Rn][Gn];
    __shared__ float mk_l[Rn];

    if (tid < Rn) mk_l[tid] = mask[row0 + tid] ? 1.f : 0.f;

    // ---- per-row group means (16 lanes per group)
    const int g = tid >> 4;
#pragma unroll
    for (int i = 0; i < Rn; ++i) {
        float s = (xv[i].x + xv[i].y) + (xv[i].z + xv[i].w);
        s += __shfl_xor(s, 1);
        s += __shfl_xor(s, 2);
        s += __shfl_xor(s, 4);
        s += __shfl_xor(s, 8);
        if ((tid & 15) == 0) m_l[i][g] = s * (1.f / (float)GSn);
    }
    __syncthreads();

    // ---- chunk scan: thread (sg, r), width-8 segmented inclusive scan
    if (tid < Gn * Rn) {
        const int sg = tid >> 3, r = tid & 7;
        const float mm = m_l[r][sg];
        const float kk = mk_l[r];
        float S = kk * mm, Q = kk * mm * mm, P = kk;
#pragma unroll
        for (int off = 1; off < Rn; off <<= 1) {
            float u;
            u = __shfl_up(S, off, Rn); if (r >= off) S += u;
            u = __shfl_up(Q, off, Rn); if (r >= off) Q += u;
            u = __shfl_up(P, off, Rn); if (r >= off) P += u;
        }
        iS_l[r][sg] = S; iQ_l[r][sg] = Q; iP_l[r][sg] = P;
        if (r == Rn - 1) {
            aS_l[sg] = S; aQ_l[sg] = Q; aP_l[sg] = P;
            if (c > 0) {
                __hip_atomic_store(&aggS[T * Gn + sg], S, __ATOMIC_RELAXED, __HIP_MEMORY_SCOPE_AGENT);
                __hip_atomic_store(&aggQ[T * Gn + sg], Q, __ATOMIC_RELAXED, __HIP_MEMORY_SCOPE_AGENT);
                __hip_atomic_store(&aggP[T * Gn + sg], P, __ATOMIC_RELAXED, __HIP_MEMORY_SCOPE_AGENT);
            }
        }
    }
    __syncthreads();   // every wave drains vmcnt before s_barrier -> aggs visible

    // ---- publish flag, lookback, publish inclusive (wave 0)
    if (tid < 64) {
        if (tid == 0 && c > 0)
            __hip_atomic_store(&flags[T], 1u, __ATOMIC_RELEASE, __HIP_MEMORY_SCOPE_AGENT);
        if (tid < Gn) {
            float eS = 0.f, eQ = 0.f, eP = 0.f;
            if (c > 0) {
                int cp = T - 1;
                while (true) {
                    const unsigned f = __hip_atomic_load(&flags[cp], __ATOMIC_RELAXED, __HIP_MEMORY_SCOPE_AGENT);
                    if (f == 0u) { __builtin_amdgcn_s_sleep(1); continue; }
                    if (f == 2u) {
                        eS += __hip_atomic_load(&incS[cp * Gn + tid], __ATOMIC_RELAXED, __HIP_MEMORY_SCOPE_AGENT);
                        eQ += __hip_atomic_load(&incQ[cp * Gn + tid], __ATOMIC_RELAXED, __HIP_MEMORY_SCOPE_AGENT);
                        eP += __hip_atomic_load(&incP[cp * Gn + tid], __ATOMIC_RELAXED, __HIP_MEMORY_SCOPE_AGENT);
                        break;
                    }
                    eS += __hip_atomic_load(&aggS[cp * Gn + tid], __ATOMIC_RELAXED, __HIP_MEMORY_SCOPE_AGENT);
                    eQ += __hip_atomic_load(&aggQ[cp * Gn + tid], __ATOMIC_RELAXED, __HIP_MEMORY_SCOPE_AGENT);
                    eP += __hip_atomic_load(&aggP[cp * Gn + tid], __ATOMIC_RELAXED, __HIP_MEMORY_SCOPE_AGENT);
                    --cp;
                }
            }
            eS_l[tid] = eS; eQ_l[tid] = eQ; eP_l[tid] = eP;
            const float tS = eS + aS_l[tid];
            const float tQ = eQ + aQ_l[tid];
            const float tP = eP + aP_l[tid];
            __hip_atomic_store(&incS[T * Gn + tid], tS, __ATOMIC_RELAXED, __HIP_MEMORY_SCOPE_AGENT);
            __hip_atomic_store(&incQ[T * Gn + tid], tQ, __ATOMIC_RELAXED, __HIP_MEMORY_SCOPE_AGENT);
            __hip_atomic_store(&incP[T * Gn + tid], tP, __ATOMIC_RELAXED, __HIP_MEMORY_SCOPE_AGENT);
            if (c == CPB - 1) {           // final per-(b,g) stats
                const float c0  = (float)prev_count[b];
                const float mu0 = prev_mean[b * Gn + tid];
                const float v0  = prev_var[b * Gn + tid];
                const float A0  = c0 * mu0;
                const float M2b = v0 * fmaxf(c0, 1.f) + c0 * mu0 * mu0;
                const float cs  = fmaxf(c0 + tP, 1.f);
                const float mean = (A0 + tS) / cs;
                out_mean[b * Gn + tid] = mean;
                out_var[b * Gn + tid]  = (M2b + tQ) / cs - mean * mean;
                if (tid == 0) out_count[b] = c0 + tP;
            }
        }
        if (tid == 0)                     // release waits wave's vmcnt -> incs done
            __hip_atomic_store(&flags[T], 2u, __ATOMIC_RELEASE, __HIP_MEMORY_SCOPE_AGENT);
    }
    __syncthreads();

    // ---- per-(row,g) Welford finalize -> LDS
    if (tid < Gn * Rn) {
        const int sg = tid >> 3, r = tid & 7;
        const float c0  = (float)prev_count[b];
        const float mu0 = prev_mean[b * Gn + sg];
        const float v0  = prev_var[b * Gn + sg];
        const float A0  = c0 * mu0;
        const float M2b = v0 * fmaxf(c0, 1.f) + c0 * mu0 * mu0;
        const float S = eS_l[sg] + iS_l[r][sg];
        const float Q = eQ_l[sg] + iQ_l[r][sg];
        const float P = eP_l[sg] + iP_l[r][sg];
        const float cs = fmaxf(c0 + P, 1.f);
        const float rc = __builtin_amdgcn_rcpf(cs);
        const float mean = (A0 + S) * rc;
        const float var  = (M2b + Q) * rc - mean * mean;
        me_l[r][sg] = mean;
        rs_l[r][sg] = rsqrtf(var + EPS);
    }
    __syncthreads();

    // ---- normalize payload, contiguous nt-store
    {
        float* yp = y + (size_t)row0 * Dn + tid * 4;
#pragma unroll
        for (int i = 0; i < Rn; ++i) {
            const float me = me_l[i][g];
            const float rs = rs_l[i][g];
            f4 o;
            o.x = (xv[i].x - me) * rs * w4.x + b4.x;
            o.y = (xv[i].y - me) * rs * w4.y + b4.y;
            o.z = (xv[i].z - me) * rs * w4.z + b4.z;
            o.w = (xv[i].w - me) * rs * w4.w + b4.w;
            __builtin_nontemporal_store(o, reinterpret_cast<f4*>(yp + (size_t)i * Dn));
        }
    }
}

// ---------------------------------------------------------------------------
extern "C" void kernel_launch(void* const* d_in, const int* in_sizes, int n_in,
                              void* d_out, int out_size, void* d_ws, size_t ws_size,
                              hipStream_t stream) {
    (void)in_sizes; (void)n_in; (void)out_size; (void)ws_size;

    const float* x          = (const float*)d_in[0];
    const int*   mask       = (const int*)d_in[1];     // bool pushed as int32
    const int*   prev_count = (const int*)d_in[2];     // int pushed as int32
    const float* prev_mean  = (const float*)d_in[3];
    const float* prev_var   = (const float*)d_in[4];
    const float* weight     = (const float*)d_in[5];
    const float* bias       = (const float*)d_in[6];

    float* out = (float*)d_out;
    float* y         = out;                                   // B*L*D
    float* out_count = out + (size_t)Bn * Ln * Dn;            // B
    float* out_mean  = out_count + Bn;                        // B*G
    float* out_var   = out_mean + (size_t)Bn * Gn;            // B*G

    // ws layout: ticket | flags[NCHUNK] | agg S/Q/P | inc S/Q/P
    unsigned* ticket = (unsigned*)d_ws;
    unsigned* flags  = ticket + 16;                   // 64-B offset
    float* fb = (float*)(flags + NCHUNK);
    const size_t NW = (size_t)NCHUNK * Gn;            // 131072
    float* aggS = fb;            float* aggQ = aggS + NW;  float* aggP = aggQ + NW;
    float* incS = aggP + NW;     float* incQ = incS + NW;  float* incP = incQ + NW;

    k_init<<<(NCHUNK + 511) / 512, 512, 0, stream>>>(flags, ticket);
    scan_norm<<<NCHUNK, 512, 0, stream>>>(x, mask, prev_count, prev_mean, prev_var,
                                          weight, bias, y, out_count, out_mean, out_var,
                                          ticket, flags, aggS, aggQ, aggP, incS, incQ, incP);
}

// Round 14
// 106.451 us; speedup vs baseline: 4.4722x; 4.4722x over previous
//
#include <hip/hip_runtime.h>
#include <cstdint>

// Problem constants (match reference)
#define Bn 8
#define Ln 4096
#define Dn 2048
#define Gn 32
#define GSn 64
#define TROWS 256               // timesteps per tile: 1024 threads x (4 rows) x 16 lanes
#define NT (Ln / TROWS)         // 16 tiles per chain
static constexpr float EPS = 1e-5f;

// Native vector type for nontemporal builtins (HIP float4 is rejected).
typedef float f4 __attribute__((ext_vector_type(4)));

// Raw barrier: orders only LDS (lgkmcnt), NOT vmcnt — prefetched global loads
// stay in flight across it (__syncthreads would drain vmcnt(0) per tile with
// nothing to hide the stall under at 1 block/CU).
#define LDS_BARRIER()                                            \
    do {                                                         \
        asm volatile("s_waitcnt lgkmcnt(0)" ::: "memory");       \
        __builtin_amdgcn_s_barrier();                            \
        asm volatile("" ::: "memory");                           \
    } while (0)

// ---------------------------------------------------------------------------
// One block per (b,g) chain, single pass (round-12 champion) + XCD swizzle:
// b = blk&7, g = blk>>3. MI355X dispatches blockIdx round-robin over 8 XCDs,
// so all 32 chains of batch b land on XCD b — their adjacent 256-B column
// slabs merge into contiguous row streams at that XCD's L2 (round-13 showed
// contiguity is worth ~20% BW; this gets it without changing decomposition).
// Thread (pr,k): rows 4pr..4pr+3 of the tile, 16 lanes x f4 = 64 cols.
// Per tile: 4 row group-means (shfl_xor butterfly); thread (S,Q,P) partials;
// in-wave scan over 4 sub-groups; leaders post to double-buffered LDS;
// LDS_BARRIER; every wave scans the 16 wave totals in-register; closed-form
// Welford per row; normalize in registers; nontemporal store.
// x read once, y written once; no workspace, no grid sync.
// mask (bool) and prev_count (int64) are pushed by the harness as int32.
// ---------------------------------------------------------------------------
__global__ __launch_bounds__(1024, 1) void fused_chain(
    const float* __restrict__ x,
    const int* __restrict__ mask,
    const int* __restrict__ prev_count,
    const float* __restrict__ prev_mean,
    const float* __restrict__ prev_var,
    const float* __restrict__ weight,
    const float* __restrict__ bias,
    float* __restrict__ y,
    float* __restrict__ out_count,
    float* __restrict__ out_mean,
    float* __restrict__ out_var)
{
    const int blk = blockIdx.x;
    const int b   = blk & 7;         // XCD swizzle: batch -> XCD
    const int g   = blk >> 3;        // 32 groups of batch b share one XCD
    const int bg  = b * Gn + g;
    const int tid = threadIdx.x;
    const int k    = tid & 15;       // 16 lanes per row
    const int pr   = tid >> 4;       // quad index 0..63 (rows 4pr..4pr+3)
    const int lane = tid & 63;
    const int wv   = tid >> 6;       // wave 0..15

    const size_t xbase = (size_t)b * Ln * Dn + g * GSn + k * 4;
    const int    mbase = b * Ln;

    const f4 wv4 = *reinterpret_cast<const f4*>(weight + g * GSn + k * 4);
    const f4 bv4 = *reinterpret_cast<const f4*>(bias   + g * GSn + k * 4);

    const float c0  = (float)prev_count[b];
    const float mu0 = prev_mean[bg];
    const float v0  = prev_var[bg];
    const float A0  = c0 * mu0;
    const float M2b = v0 * fmaxf(c0, 1.f) + c0 * mu0 * mu0;

    __shared__ float wTot[2][3][16];   // double-buffered per-wave totals

    float carS = 0.f, carQ = 0.f, carP = 0.f;   // carry across tiles (uniform)

    // prefetch tile 0 (4 rows/thread, nontemporal: touch-once stream)
    f4 xc0, xc1, xc2, xc3;
    int4 mkc;
    {
        const int r0 = 4 * pr;
        xc0 = __builtin_nontemporal_load(reinterpret_cast<const f4*>(x + xbase + (size_t)(r0 + 0) * Dn));
        xc1 = __builtin_nontemporal_load(reinterpret_cast<const f4*>(x + xbase + (size_t)(r0 + 1) * Dn));
        xc2 = __builtin_nontemporal_load(reinterpret_cast<const f4*>(x + xbase + (size_t)(r0 + 2) * Dn));
        xc3 = __builtin_nontemporal_load(reinterpret_cast<const f4*>(x + xbase + (size_t)(r0 + 3) * Dn));
        mkc = *reinterpret_cast<const int4*>(mask + mbase + r0);
    }

    for (int it = 0; it < NT; ++it) {
        // ---- issue prefetch for tile it+1 (consumed after a full tile of work)
        const int rn = (it + 1 < NT) ? ((it + 1) * TROWS + 4 * pr) : 4 * pr;
        f4 xn0 = __builtin_nontemporal_load(reinterpret_cast<const f4*>(x + xbase + (size_t)(rn + 0) * Dn));
        f4 xn1 = __builtin_nontemporal_load(reinterpret_cast<const f4*>(x + xbase + (size_t)(rn + 1) * Dn));
        f4 xn2 = __builtin_nontemporal_load(reinterpret_cast<const f4*>(x + xbase + (size_t)(rn + 2) * Dn));
        f4 xn3 = __builtin_nontemporal_load(reinterpret_cast<const f4*>(x + xbase + (size_t)(rn + 3) * Dn));
        int4 mkn = *reinterpret_cast<const int4*>(mask + mbase + rn);

        // ---- row group-means (butterfly over 16 lanes; all lanes get the sum)
        float s0 = (xc0.x + xc0.y) + (xc0.z + xc0.w);
        float s1 = (xc1.x + xc1.y) + (xc1.z + xc1.w);
        float s2 = (xc2.x + xc2.y) + (xc2.z + xc2.w);
        float s3 = (xc3.x + xc3.y) + (xc3.z + xc3.w);
#pragma unroll
        for (int off = 1; off < 16; off <<= 1) {
            s0 += __shfl_xor(s0, off);
            s1 += __shfl_xor(s1, off);
            s2 += __shfl_xor(s2, off);
            s3 += __shfl_xor(s3, off);
        }
        const float m0 = s0 * (1.f / (float)GSn);
        const float m1 = s1 * (1.f / (float)GSn);
        const float m2 = s2 * (1.f / (float)GSn);
        const float m3 = s3 * (1.f / (float)GSn);
        const float k0 = mkc.x ? 1.f : 0.f;
        const float k1 = mkc.y ? 1.f : 0.f;
        const float k2 = mkc.z ? 1.f : 0.f;
        const float k3 = mkc.w ? 1.f : 0.f;

        // ---- thread-local partials over its 4 rows
        const float S = k0 * m0 + k1 * m1 + k2 * m2 + k3 * m3;
        const float Q = k0 * m0 * m0 + k1 * m1 * m1 + k2 * m2 * m2 + k3 * m3 * m3;
        const float P = k0 + k1 + k2 + k3;

        // ---- in-wave inclusive scan across the 4 sub-groups (16-lane each)
        float iS = S, iQ = Q, iP = P;
        {
            float u;
            u = __shfl_up(iS, 16); if (lane >= 16) iS += u;
            u = __shfl_up(iQ, 16); if (lane >= 16) iQ += u;
            u = __shfl_up(iP, 16); if (lane >= 16) iP += u;
            u = __shfl_up(iS, 32); if (lane >= 32) iS += u;
            u = __shfl_up(iQ, 32); if (lane >= 32) iQ += u;
            u = __shfl_up(iP, 32); if (lane >= 32) iP += u;
        }

        const int p = it & 1;
        if (lane == 63) { wTot[p][0][wv] = iS; wTot[p][1][wv] = iQ; wTot[p][2][wv] = iP; }
        LDS_BARRIER();

        // ---- every wave scans the 16 wave totals in-register
        float tS = wTot[p][0][k];
        float tQ = wTot[p][1][k];
        float tP = wTot[p][2][k];
#pragma unroll
        for (int off = 1; off < 16; off <<= 1) {
            float u;
            u = __shfl_up(tS, off, 16); if (k >= off) tS += u;
            u = __shfl_up(tQ, off, 16); if (k >= off) tQ += u;
            u = __shfl_up(tP, off, 16); if (k >= off) tP += u;
        }
        const float tileS = __shfl(tS, 15, 16);
        const float tileQ = __shfl(tQ, 15, 16);
        const float tileP = __shfl(tP, 15, 16);
        const int j = (wv == 0) ? 0 : wv - 1;
        float exS = __shfl(tS, j, 16);
        float exQ = __shfl(tQ, j, 16);
        float exP = __shfl(tP, j, 16);
        if (wv == 0) { exS = 0.f; exQ = 0.f; exP = 0.f; }

        // ---- running prefix for this thread's 4 rows, Welford + store
        float bS = carS + exS + (iS - S);
        float bQ = carQ + exQ + (iQ - Q);
        float bP = carP + exP + (iP - P);
        const size_t yrow = xbase + (size_t)(it * TROWS + 4 * pr) * Dn;

        {
            bS += k0 * m0; bQ += k0 * m0 * m0; bP += k0;
            const float rc = __builtin_amdgcn_rcpf(fmaxf(c0 + bP, 1.f));
            const float me = (A0 + bS) * rc;
            const float rs = rsqrtf((M2b + bQ) * rc - me * me + EPS);
            f4 o;
            o.x = (xc0.x - me) * rs * wv4.x + bv4.x;
            o.y = (xc0.y - me) * rs * wv4.y + bv4.y;
            o.z = (xc0.z - me) * rs * wv4.z + bv4.z;
            o.w = (xc0.w - me) * rs * wv4.w + bv4.w;
            __builtin_nontemporal_store(o, reinterpret_cast<f4*>(y + yrow));
        }
        {
            bS += k1 * m1; bQ += k1 * m1 * m1; bP += k1;
            const float rc = __builtin_amdgcn_rcpf(fmaxf(c0 + bP, 1.f));
            const float me = (A0 + bS) * rc;
            const float rs = rsqrtf((M2b + bQ) * rc - me * me + EPS);
            f4 o;
            o.x = (xc1.x - me) * rs * wv4.x + bv4.x;
            o.y = (xc1.y - me) * rs * wv4.y + bv4.y;
            o.z = (xc1.z - me) * rs * wv4.z + bv4.z;
            o.w = (xc1.w - me) * rs * wv4.w + bv4.w;
            __builtin_nontemporal_store(o, reinterpret_cast<f4*>(y + yrow + Dn));
        }
        {
            bS += k2 * m2; bQ += k2 * m2 * m2; bP += k2;
            const float rc = __builtin_amdgcn_rcpf(fmaxf(c0 + bP, 1.f));
            const float me = (A0 + bS) * rc;
            const float rs = rsqrtf((M2b + bQ) * rc - me * me + EPS);
            f4 o;
            o.x = (xc2.x - me) * rs * wv4.x + bv4.x;
            o.y = (xc2.y - me) * rs * wv4.y + bv4.y;
            o.z = (xc2.z - me) * rs * wv4.z + bv4.z;
            o.w = (xc2.w - me) * rs * wv4.w + bv4.w;
            __builtin_nontemporal_store(o, reinterpret_cast<f4*>(y + yrow + 2 * Dn));
        }
        {
            bS += k3 * m3; bQ += k3 * m3 * m3; bP += k3;
            const float rc = __builtin_amdgcn_rcpf(fmaxf(c0 + bP, 1.f));
            const float me = (A0 + bS) * rc;
            const float rs = rsqrtf((M2b + bQ) * rc - me * me + EPS);
            f4 o;
            o.x = (xc3.x - me) * rs * wv4.x + bv4.x;
            o.y = (xc3.y - me) * rs * wv4.y + bv4.y;
            o.z = (xc3.z - me) * rs * wv4.z + bv4.z;
            o.w = (xc3.w - me) * rs * wv4.w + bv4.w;
            __builtin_nontemporal_store(o, reinterpret_cast<f4*>(y + yrow + 3 * Dn));
        }

        // ---- advance carry (uniform), rotate prefetch
        carS += tileS; carQ += tileQ; carP += tileP;
        xc0 = xn0; xc1 = xn1; xc2 = xn2; xc3 = xn3; mkc = mkn;
    }

    if (tid == 0) {
        const float c  = c0 + carP;
        const float cs = fmaxf(c, 1.f);
        const float mean = (A0 + carS) / cs;
        out_mean[bg] = mean;
        out_var[bg]  = (M2b + carQ) / cs - mean * mean;
        if (g == 0) out_count[b] = c;
    }
}

// ---------------------------------------------------------------------------
extern "C" void kernel_launch(void* const* d_in, const int* in_sizes, int n_in,
                              void* d_out, int out_size, void* d_ws, size_t ws_size,
                              hipStream_t stream) {
    (void)in_sizes; (void)n_in; (void)out_size; (void)d_ws; (void)ws_size;

    const float* x          = (const float*)d_in[0];
    const int*   mask       = (const int*)d_in[1];     // bool pushed as int32
    const int*   prev_count = (const int*)d_in[2];     // int pushed as int32
    const float* prev_mean  = (const float*)d_in[3];
    const float* prev_var   = (const float*)d_in[4];
    const float* weight     = (const float*)d_in[5];
    const float* bias       = (const float*)d_in[6];

    float* out = (float*)d_out;
    float* y         = out;                                   // B*L*D
    float* out_count = out + (size_t)Bn * Ln * Dn;            // B
    float* out_mean  = out_count + Bn;                        // B*G
    float* out_var   = out_mean + (size_t)Bn * Gn;            // B*G

    fused_chain<<<Bn * Gn, 1024, 0, stream>>>(x, mask, prev_count, prev_mean,
                                              prev_var, weight, bias, y,
                                              out_count, out_mean, out_var);
}

// Round 15
// 82.395 us; speedup vs baseline: 5.7779x; 1.2920x over previous
//
#include <hip/hip_runtime.h>
#include <cstdint>

// Problem constants (match reference)
#define Bn 8
#define Ln 4096
#define Dn 2048
#define Gn 32
#define GSn 64
#define TROWS 256               // timesteps per tile: 1024 threads x (4 rows) x 16 lanes
#define NT (Ln / TROWS)         // 16 tiles per chain
static constexpr float EPS = 1e-5f;

// Native vector type for nontemporal builtins (HIP float4 is rejected).
typedef float f4 __attribute__((ext_vector_type(4)));

// Raw barrier: orders only LDS (lgkmcnt), NOT vmcnt — prefetched global loads
// stay in flight across it (__syncthreads would drain vmcnt(0) per tile with
// nothing to hide the stall under at 1 block/CU).
#define LDS_BARRIER()                                            \
    do {                                                         \
        asm volatile("s_waitcnt lgkmcnt(0)" ::: "memory");       \
        __builtin_amdgcn_s_barrier();                            \
        asm volatile("" ::: "memory");                           \
    } while (0)

// ---------------------------------------------------------------------------
// One block per (b,g) chain, single pass + XCD swizzle (b = blk&7 -> all 32
// chains of batch b on one XCD; their adjacent 256-B slabs merge into
// contiguous row streams at that XCD's L2).
// CACHE POLICY (this round's change): x loads are TEMPORAL (L3 may retain x
// across graph replays — x is 268 MB vs 256 MB L3), y stores NONTEMPORAL
// (y's 268 MB must not evict x). Round-13 evidence: contiguous kernel saw
// FETCH=138MB (retention works when y doesn't pollute); r12's nt-loads
// marked x itself no-allocate, defeating retention.
// Thread (pr,k): rows 4pr..4pr+3 of the tile, 16 lanes x f4 = 64 cols.
// Per tile: 4 row group-means (shfl_xor butterfly); thread (S,Q,P) partials;
// in-wave scan over 4 sub-groups; leaders post to double-buffered LDS;
// LDS_BARRIER; every wave scans the 16 wave totals in-register; closed-form
// Welford per row; normalize in registers; nt-store.
// x read once, y written once; no workspace, no grid sync.
// mask (bool) and prev_count (int64) are pushed by the harness as int32.
// ---------------------------------------------------------------------------
__global__ __launch_bounds__(1024, 1) void fused_chain(
    const float* __restrict__ x,
    const int* __restrict__ mask,
    const int* __restrict__ prev_count,
    const float* __restrict__ prev_mean,
    const float* __restrict__ prev_var,
    const float* __restrict__ weight,
    const float* __restrict__ bias,
    float* __restrict__ y,
    float* __restrict__ out_count,
    float* __restrict__ out_mean,
    float* __restrict__ out_var)
{
    const int blk = blockIdx.x;
    const int b   = blk & 7;         // XCD swizzle: batch -> XCD
    const int g   = blk >> 3;        // 32 groups of batch b share one XCD
    const int bg  = b * Gn + g;
    const int tid = threadIdx.x;
    const int k    = tid & 15;       // 16 lanes per row
    const int pr   = tid >> 4;       // quad index 0..63 (rows 4pr..4pr+3)
    const int lane = tid & 63;
    const int wv   = tid >> 6;       // wave 0..15

    const size_t xbase = (size_t)b * Ln * Dn + g * GSn + k * 4;
    const int    mbase = b * Ln;

    const f4 wv4 = *reinterpret_cast<const f4*>(weight + g * GSn + k * 4);
    const f4 bv4 = *reinterpret_cast<const f4*>(bias   + g * GSn + k * 4);

    const float c0  = (float)prev_count[b];
    const float mu0 = prev_mean[bg];
    const float v0  = prev_var[bg];
    const float A0  = c0 * mu0;
    const float M2b = v0 * fmaxf(c0, 1.f) + c0 * mu0 * mu0;

    __shared__ float wTot[2][3][16];   // double-buffered per-wave totals

    float carS = 0.f, carQ = 0.f, carP = 0.f;   // carry across tiles (uniform)

    // prefetch tile 0 (4 rows/thread; temporal loads -> L3 may retain x)
    f4 xc0, xc1, xc2, xc3;
    int4 mkc;
    {
        const int r0 = 4 * pr;
        xc0 = *reinterpret_cast<const f4*>(x + xbase + (size_t)(r0 + 0) * Dn);
        xc1 = *reinterpret_cast<const f4*>(x + xbase + (size_t)(r0 + 1) * Dn);
        xc2 = *reinterpret_cast<const f4*>(x + xbase + (size_t)(r0 + 2) * Dn);
        xc3 = *reinterpret_cast<const f4*>(x + xbase + (size_t)(r0 + 3) * Dn);
        mkc = *reinterpret_cast<const int4*>(mask + mbase + r0);
    }

    for (int it = 0; it < NT; ++it) {
        // ---- issue prefetch for tile it+1 (consumed after a full tile of work)
        const int rn = (it + 1 < NT) ? ((it + 1) * TROWS + 4 * pr) : 4 * pr;
        f4 xn0 = *reinterpret_cast<const f4*>(x + xbase + (size_t)(rn + 0) * Dn);
        f4 xn1 = *reinterpret_cast<const f4*>(x + xbase + (size_t)(rn + 1) * Dn);
        f4 xn2 = *reinterpret_cast<const f4*>(x + xbase + (size_t)(rn + 2) * Dn);
        f4 xn3 = *reinterpret_cast<const f4*>(x + xbase + (size_t)(rn + 3) * Dn);
        int4 mkn = *reinterpret_cast<const int4*>(mask + mbase + rn);

        // ---- row group-means (butterfly over 16 lanes; all lanes get the sum)
        float s0 = (xc0.x + xc0.y) + (xc0.z + xc0.w);
        float s1 = (xc1.x + xc1.y) + (xc1.z + xc1.w);
        float s2 = (xc2.x + xc2.y) + (xc2.z + xc2.w);
        float s3 = (xc3.x + xc3.y) + (xc3.z + xc3.w);
#pragma unroll
        for (int off = 1; off < 16; off <<= 1) {
            s0 += __shfl_xor(s0, off);
            s1 += __shfl_xor(s1, off);
            s2 += __shfl_xor(s2, off);
            s3 += __shfl_xor(s3, off);
        }
        const float m0 = s0 * (1.f / (float)GSn);
        const float m1 = s1 * (1.f / (float)GSn);
        const float m2 = s2 * (1.f / (float)GSn);
        const float m3 = s3 * (1.f / (float)GSn);
        const float k0 = mkc.x ? 1.f : 0.f;
        const float k1 = mkc.y ? 1.f : 0.f;
        const float k2 = mkc.z ? 1.f : 0.f;
        const float k3 = mkc.w ? 1.f : 0.f;

        // ---- thread-local partials over its 4 rows
        const float S = k0 * m0 + k1 * m1 + k2 * m2 + k3 * m3;
        const float Q = k0 * m0 * m0 + k1 * m1 * m1 + k2 * m2 * m2 + k3 * m3 * m3;
        const float P = k0 + k1 + k2 + k3;

        // ---- in-wave inclusive scan across the 4 sub-groups (16-lane each)
        float iS = S, iQ = Q, iP = P;
        {
            float u;
            u = __shfl_up(iS, 16); if (lane >= 16) iS += u;
            u = __shfl_up(iQ, 16); if (lane >= 16) iQ += u;
            u = __shfl_up(iP, 16); if (lane >= 16) iP += u;
            u = __shfl_up(iS, 32); if (lane >= 32) iS += u;
            u = __shfl_up(iQ, 32); if (lane >= 32) iQ += u;
            u = __shfl_up(iP, 32); if (lane >= 32) iP += u;
        }

        const int p = it & 1;
        if (lane == 63) { wTot[p][0][wv] = iS; wTot[p][1][wv] = iQ; wTot[p][2][wv] = iP; }
        LDS_BARRIER();

        // ---- every wave scans the 16 wave totals in-register
        float tS = wTot[p][0][k];
        float tQ = wTot[p][1][k];
        float tP = wTot[p][2][k];
#pragma unroll
        for (int off = 1; off < 16; off <<= 1) {
            float u;
            u = __shfl_up(tS, off, 16); if (k >= off) tS += u;
            u = __shfl_up(tQ, off, 16); if (k >= off) tQ += u;
            u = __shfl_up(tP, off, 16); if (k >= off) tP += u;
        }
        const float tileS = __shfl(tS, 15, 16);
        const float tileQ = __shfl(tQ, 15, 16);
        const float tileP = __shfl(tP, 15, 16);
        const int j = (wv == 0) ? 0 : wv - 1;
        float exS = __shfl(tS, j, 16);
        float exQ = __shfl(tQ, j, 16);
        float exP = __shfl(tP, j, 16);
        if (wv == 0) { exS = 0.f; exQ = 0.f; exP = 0.f; }

        // ---- running prefix for this thread's 4 rows, Welford + store
        float bS = carS + exS + (iS - S);
        float bQ = carQ + exQ + (iQ - Q);
        float bP = carP + exP + (iP - P);
        const size_t yrow = xbase + (size_t)(it * TROWS + 4 * pr) * Dn;

        {
            bS += k0 * m0; bQ += k0 * m0 * m0; bP += k0;
            const float rc = __builtin_amdgcn_rcpf(fmaxf(c0 + bP, 1.f));
            const float me = (A0 + bS) * rc;
            const float rs = rsqrtf((M2b + bQ) * rc - me * me + EPS);
            f4 o;
            o.x = (xc0.x - me) * rs * wv4.x + bv4.x;
            o.y = (xc0.y - me) * rs * wv4.y + bv4.y;
            o.z = (xc0.z - me) * rs * wv4.z + bv4.z;
            o.w = (xc0.w - me) * rs * wv4.w + bv4.w;
            __builtin_nontemporal_store(o, reinterpret_cast<f4*>(y + yrow));
        }
        {
            bS += k1 * m1; bQ += k1 * m1 * m1; bP += k1;
            const float rc = __builtin_amdgcn_rcpf(fmaxf(c0 + bP, 1.f));
            const float me = (A0 + bS) * rc;
            const float rs = rsqrtf((M2b + bQ) * rc - me * me + EPS);
            f4 o;
            o.x = (xc1.x - me) * rs * wv4.x + bv4.x;
            o.y = (xc1.y - me) * rs * wv4.y + bv4.y;
            o.z = (xc1.z - me) * rs * wv4.z + bv4.z;
            o.w = (xc1.w - me) * rs * wv4.w + bv4.w;
            __builtin_nontemporal_store(o, reinterpret_cast<f4*>(y + yrow + Dn));
        }
        {
            bS += k2 * m2; bQ += k2 * m2 * m2; bP += k2;
            const float rc = __builtin_amdgcn_rcpf(fmaxf(c0 + bP, 1.f));
            const float me = (A0 + bS) * rc;
            const float rs = rsqrtf((M2b + bQ) * rc - me * me + EPS);
            f4 o;
            o.x = (xc2.x - me) * rs * wv4.x + bv4.x;
            o.y = (xc2.y - me) * rs * wv4.y + bv4.y;
            o.z = (xc2.z - me) * rs * wv4.z + bv4.z;
            o.w = (xc2.w - me) * rs * wv4.w + bv4.w;
            __builtin_nontemporal_store(o, reinterpret_cast<f4*>(y + yrow + 2 * Dn));
        }
        {
            bS += k3 * m3; bQ += k3 * m3 * m3; bP += k3;
            const float rc = __builtin_amdgcn_rcpf(fmaxf(c0 + bP, 1.f));
            const float me = (A0 + bS) * rc;
            const float rs = rsqrtf((M2b + bQ) * rc - me * me + EPS);
            f4 o;
            o.x = (xc3.x - me) * rs * wv4.x + bv4.x;
            o.y = (xc3.y - me) * rs * wv4.y + bv4.y;
            o.z = (xc3.z - me) * rs * wv4.z + bv4.z;
            o.w = (xc3.w - me) * rs * wv4.w + bv4.w;
            __builtin_nontemporal_store(o, reinterpret_cast<f4*>(y + yrow + 3 * Dn));
        }

        // ---- advance carry (uniform), rotate prefetch
        carS += tileS; carQ += tileQ; carP += tileP;
        xc0 = xn0; xc1 = xn1; xc2 = xn2; xc3 = xn3; mkc = mkn;
    }

    if (tid == 0) {
        const float c  = c0 + carP;
        const float cs = fmaxf(c, 1.f);
        const float mean = (A0 + carS) / cs;
        out_mean[bg] = mean;
        out_var[bg]  = (M2b + carQ) / cs - mean * mean;
        if (g == 0) out_count[b] = c;
    }
}

// ---------------------------------------------------------------------------
extern "C" void kernel_launch(void* const* d_in, const int* in_sizes, int n_in,
                              void* d_out, int out_size, void* d_ws, size_t ws_size,
                              hipStream_t stream) {
    (void)in_sizes; (void)n_in; (void)out_size; (void)d_ws; (void)ws_size;

    const float* x          = (const float*)d_in[0];
    const int*   mask       = (const int*)d_in[1];     // bool pushed as int32
    const int*   prev_count = (const int*)d_in[2];     // int pushed as int32
    const float* prev_mean  = (const float*)d_in[3];
    const float* prev_var   = (const float*)d_in[4];
    const float* weight     = (const float*)d_in[5];
    const float* bias       = (const float*)d_in[6];

    float* out = (float*)d_out;
    float* y         = out;                                   // B*L*D
    float* out_count = out + (size_t)Bn * Ln * Dn;            // B
    float* out_mean  = out_count + Bn;                        // B*G
    float* out_var   = out_mean + (size_t)Bn * Gn;            // B*G

    fused_chain<<<Bn * Gn, 1024, 0, stream>>>(x, mask, prev_count, prev_mean,
                                              prev_var, weight, bias, y,
                                              out_count, out_mean, out_var);
}